// Round 4
// baseline (793.187 us; speedup 1.0000x reference)
//
#include <hip/hip_runtime.h>
#include <hip/hip_bf16.h>

typedef __hip_bfloat16 bf16;

// Problem constants
#define BB    4
#define LQ    4096
#define LIN   16464
#define DM    768
#define NH    12
#define HD    64
#define K_DIM 768
// Levels: (112,112),(56,56),(28,28); starts 0,12544,15680; query grid 64x64

typedef __attribute__((ext_vector_type(8))) __bf16 bfrag;
typedef __attribute__((ext_vector_type(4))) float  ffrag;

// ---------------------------------------------------------------------------
// async global->LDS 16B per lane (LDS dest is wave-uniform base + lane*16)
// ---------------------------------------------------------------------------
__device__ __forceinline__ void g2l16(const void* g, void* l) {
    __builtin_amdgcn_global_load_lds(
        (const __attribute__((address_space(1))) void*)g,
        (__attribute__((address_space(3))) void*)l, 16, 0, 0);
}

// bijective XCD-chunk swizzle (m204): dispatch i lands on XCD i%8; give each
// XCD a contiguous run of logical ids so neighbor work shares its private L2.
__device__ __forceinline__ int xcd_swz(int orig, int nwg) {
    int xcd = orig & 7, within = orig >> 3;
    int q = nwg >> 3, r = nwg & 7;
    return (xcd < r ? xcd * (q + 1) : r * (q + 1) + (xcd - r) * q) + within;
}

// ---------------------------------------------------------------------------
// LayerNorm over last dim 768: one wave per row, 4 rows/block.
// ---------------------------------------------------------------------------
__global__ __launch_bounds__(256) void ln_kernel(
    const float* __restrict__ x, const float* __restrict__ g,
    const float* __restrict__ beta, bf16* __restrict__ y)
{
    int r = blockIdx.x * 4 + (threadIdx.x >> 6);
    int lane = threadIdx.x & 63;
    const float4* xr = (const float4*)(x + (size_t)r * DM);
    float4 v[3];
    #pragma unroll
    for (int i = 0; i < 3; i++) v[i] = xr[lane + 64 * i];
    float s = 0.f, ss = 0.f;
    #pragma unroll
    for (int i = 0; i < 3; i++) {
        s  += v[i].x + v[i].y + v[i].z + v[i].w;
        ss += v[i].x * v[i].x + v[i].y * v[i].y + v[i].z * v[i].z + v[i].w * v[i].w;
    }
    #pragma unroll
    for (int m = 1; m <= 32; m <<= 1) {
        s  += __shfl_xor(s, m);
        ss += __shfl_xor(ss, m);
    }
    float mean = s * (1.f / DM);
    float inv  = rsqrtf(ss * (1.f / DM) - mean * mean + 1e-6f);
    bf16* yr = y + (size_t)r * DM;
    #pragma unroll
    for (int i = 0; i < 3; i++) {
        float4 gg = ((const float4*)g)[lane + 64 * i];
        float4 bb = ((const float4*)beta)[lane + 64 * i];
        union { bf16 h[4]; uint2 u; } p;
        p.h[0] = __float2bfloat16((v[i].x - mean) * inv * gg.x + bb.x);
        p.h[1] = __float2bfloat16((v[i].y - mean) * inv * gg.y + bb.y);
        p.h[2] = __float2bfloat16((v[i].z - mean) * inv * gg.z + bb.z);
        p.h[3] = __float2bfloat16((v[i].w - mean) * inv * gg.w + bb.w);
        *(uint2*)(yr + (lane + 64 * i) * 4) = p.u;
    }
}

// ---------------------------------------------------------------------------
// Cast + transpose weights: W (768 x N f32, row-major) -> Wt (gridX*32 x 768 bf16)
// ---------------------------------------------------------------------------
__global__ __launch_bounds__(256) void cast_transpose(
    const float* __restrict__ W, bf16* __restrict__ Wt, int N)
{
    __shared__ float t[32][33];
    int n0 = blockIdx.x * 32, k0 = blockIdx.y * 32;
    int tx = threadIdx.x & 31, ty = threadIdx.x >> 5;  // ty 0..7
    #pragma unroll
    for (int i = 0; i < 4; i++) {
        int k = k0 + ty + i * 8;
        int n = n0 + tx;
        t[ty + i * 8][tx] = (n < N) ? W[(size_t)k * N + n] : 0.f;
    }
    __syncthreads();
    #pragma unroll
    for (int i = 0; i < 4; i++) {
        int n = n0 + ty + i * 8;
        Wt[(size_t)n * K_DIM + k0 + tx] = __float2bfloat16(t[tx][ty + i * 8]);
    }
}

// ---------------------------------------------------------------------------
// Shared epilogue: C/D layout col = lane&15, row = (lane>>4)*4 + reg
// ---------------------------------------------------------------------------
__device__ __forceinline__ void gemm_epilogue(
    ffrag acc[4][4], int bm, int bn, int wr, int wc, int lane,
    const float* bias, void* C, const float* resid, const float* gamma,
    const float* bias2, int M, int N, int mode, int nsplit)
{
    int mrow = lane & 15;
    int q4 = (lane >> 4) * 4;
    #pragma unroll
    for (int i = 0; i < 4; i++) {
        #pragma unroll
        for (int rr = 0; rr < 4; rr++) {
            int rg = bm + wr + i * 16 + q4 + rr;
            if (rg < M) {
                #pragma unroll
                for (int j = 0; j < 4; j++) {
                    int cg = bn + wc + j * 16 + mrow;
                    if (cg < N) {
                        float bv = (mode == 3 && cg >= nsplit) ? bias2[cg - nsplit]
                                                               : bias[cg];
                        float v = acc[i][j][rr] + bv;
                        size_t idx = (size_t)rg * N + cg;
                        if (mode == 0)      ((bf16*)C)[idx]  = __float2bfloat16(v);
                        else if (mode == 2) ((float*)C)[idx] = resid[idx] + gamma[cg] * v;
                        else                ((float*)C)[idx] = v;
                    }
                }
            }
        }
    }
}

// ---------------------------------------------------------------------------
// GEMM variant A (2-phase, for the big value GEMM): R2's relaxed
// __syncthreads structure (measured best 186us there) + XOR slot-swizzle
// (verified conflict-free in R3: SQ_LDS_BANK_CONFLICT 9.49M -> 0).
// LDS slot s of row r holds global k-octet s^((r>>1)&3) (involution applied
// on the pre-swizzled global source, rule 21); read side applies same XOR.
// ---------------------------------------------------------------------------
__global__ __launch_bounds__(256) void mfma_gemm_2ph(
    const bf16*  __restrict__ A,
    const bf16*  __restrict__ Bt,
    const float* __restrict__ bias,
    void*        __restrict__ C,
    const float* __restrict__ resid,
    const float* __restrict__ gamma,
    const float* __restrict__ bias2,
    int M, int N, int mode, int nsplit)
{
    __shared__ __align__(16) char lds[32768];   // 2 sub-tiles x (A 8K + B 8K)

    int tid  = threadIdx.x;
    int lane = tid & 63;

    int nwg  = gridDim.x * gridDim.y;
    int orig = blockIdx.y * gridDim.x + blockIdx.x;
    int wg = xcd_swz(orig, nwg);
    int bn = (wg % gridDim.x) * 128;
    int bm = (wg / gridDim.x) * 128;

    int wave = tid >> 6;
    int wr = (wave & 1) * 64, wc = (wave >> 1) * 64;

    ffrag acc[4][4] = {};

    // staging: thread covers rows rA and rA+64, slot tid&3; global k-octet
    // pre-swizzled so LDS stays linear (dest = tid*16 / tid*16+4096).
    int rA = tid >> 2;                       // 0..63
    int kb = (((tid & 3) ^ ((rA >> 1) & 3)) * 8);
    int ra0 = min(bm + rA, M - 1), ra1 = min(bm + 64 + rA, M - 1);
    const bf16* gA0 = A  + (size_t)ra0 * K_DIM + kb;
    const bf16* gA1 = A  + (size_t)ra1 * K_DIM + kb;
    const bf16* gB0 = Bt + (size_t)(bn + rA) * K_DIM + kb;
    const bf16* gB1 = Bt + (size_t)(bn + 64 + rA) * K_DIM + kb;

    int mrow = lane & 15;
    // read-side swizzled k-octet: slot = (lane>>4) ^ ((row>>1)&3)
    int kqs  = (((lane >> 4) ^ ((mrow >> 1) & 3)) * 8);

    for (int k0 = 0; k0 < K_DIM; k0 += 64) {
        #pragma unroll
        for (int s = 0; s < 2; s++) {
            char* As = lds + s * 16384;
            char* Bs = As + 8192;
            int ko = k0 + s * 32;
            g2l16(gA0 + ko, As + tid * 16);
            g2l16(gA1 + ko, As + tid * 16 + 4096);
            g2l16(gB0 + ko, Bs + tid * 16);
            g2l16(gB1 + ko, Bs + tid * 16 + 4096);
        }
        __syncthreads();
        #pragma unroll
        for (int s = 0; s < 2; s++) {
            char* As = lds + s * 16384;
            char* Bs = As + 8192;
            bfrag a[4], b[4];
            #pragma unroll
            for (int t = 0; t < 4; t++) {
                a[t] = *(const bfrag*)(As + ((wr + t * 16 + mrow) * 32 + kqs) * 2);
                b[t] = *(const bfrag*)(Bs + ((wc + t * 16 + mrow) * 32 + kqs) * 2);
            }
            #pragma unroll
            for (int i = 0; i < 4; i++)
                #pragma unroll
                for (int j = 0; j < 4; j++)
                    acc[i][j] = __builtin_amdgcn_mfma_f32_16x16x32_bf16(
                        a[i], b[j], acc[i][j], 0, 0, 0);
        }
        __syncthreads();
    }

    gemm_epilogue(acc, bm, bn, wr, wc, lane, bias, C, resid, gamma, bias2,
                  M, N, mode, nsplit);
}

// ---------------------------------------------------------------------------
// GEMM variant B (3-deep counted-vmcnt pipe, for the small/latency-bound
// comb and out GEMMs — R3 measured ~35us combined gain for them).
// ---------------------------------------------------------------------------
__global__ __launch_bounds__(256) void mfma_gemm_pipe(
    const bf16*  __restrict__ A,
    const bf16*  __restrict__ Bt,
    const float* __restrict__ bias,
    void*        __restrict__ C,
    const float* __restrict__ resid,
    const float* __restrict__ gamma,
    const float* __restrict__ bias2,
    int M, int N, int mode, int nsplit)
{
    __shared__ __align__(16) char lds[49152];   // 3 buffers x (A 8K + B 8K)

    int tid  = threadIdx.x;
    int lane = tid & 63;

    int nwg  = gridDim.x * gridDim.y;
    int orig = blockIdx.y * gridDim.x + blockIdx.x;
    int wg = xcd_swz(orig, nwg);
    int bn = (wg % gridDim.x) * 128;
    int bm = (wg / gridDim.x) * 128;

    int wave = tid >> 6;
    int wr = (wave & 1) * 64, wc = (wave >> 1) * 64;

    ffrag acc[4][4] = {};

    int rA = tid >> 2;                       // 0..63
    int kb = (((tid & 3) ^ ((rA >> 1) & 3)) * 8);
    int ra0 = min(bm + rA, M - 1), ra1 = min(bm + 64 + rA, M - 1);
    const bf16* gA0 = A  + (size_t)ra0 * K_DIM + kb;
    const bf16* gA1 = A  + (size_t)ra1 * K_DIM + kb;
    const bf16* gB0 = Bt + (size_t)(bn + rA) * K_DIM + kb;
    const bf16* gB1 = Bt + (size_t)(bn + 64 + rA) * K_DIM + kb;

    int mrow = lane & 15;
    int kqs  = (((lane >> 4) ^ ((mrow >> 1) & 3)) * 8);

    auto stage = [&](char* buf, int kt) {
        const int ko = kt * 32;
        g2l16(gA0 + ko, buf + tid * 16);
        g2l16(gA1 + ko, buf + tid * 16 + 4096);
        g2l16(gB0 + ko, buf + 8192 + tid * 16);
        g2l16(gB1 + ko, buf + 8192 + tid * 16 + 4096);
    };

    char* b0 = lds;
    char* b1 = lds + 16384;
    char* b2 = lds + 32768;
    stage(b0, 0); stage(b1, 1); stage(b2, 2);   // 12 loads in flight

    #pragma unroll
    for (int kt = 0; kt < 24; kt++) {
        if (kt + 2 < 24)      asm volatile("s_waitcnt vmcnt(8)" ::: "memory");
        else if (kt + 1 < 24) asm volatile("s_waitcnt vmcnt(4)" ::: "memory");
        else                  asm volatile("s_waitcnt vmcnt(0)" ::: "memory");
        __builtin_amdgcn_s_barrier();
        __builtin_amdgcn_sched_barrier(0);

        bfrag a[4], b[4];
        #pragma unroll
        for (int t = 0; t < 4; t++) {
            a[t] = *(const bfrag*)(b0 + ((wr + t * 16 + mrow) * 32 + kqs) * 2);
            b[t] = *(const bfrag*)(b0 + 8192 + ((wc + t * 16 + mrow) * 32 + kqs) * 2);
        }
        #pragma unroll
        for (int i = 0; i < 4; i++)
            #pragma unroll
            for (int j = 0; j < 4; j++)
                acc[i][j] = __builtin_amdgcn_mfma_f32_16x16x32_bf16(
                    a[i], b[j], acc[i][j], 0, 0, 0);

        __builtin_amdgcn_sched_barrier(0);
        __builtin_amdgcn_s_barrier();       // all waves done reading b0
        __builtin_amdgcn_sched_barrier(0);
        if (kt + 3 < 24) stage(b0, kt + 3); // refill freed buffer
        char* tp = b0; b0 = b1; b1 = b2; b2 = tp;
    }

    gemm_epilogue(acc, bm, bn, wr, wc, lane, bias, C, resid, gamma, bias2,
                  M, N, mode, nsplit);
}

// ---------------------------------------------------------------------------
// Deformable sampling, corner-parallel:
// one wave per (b,q,h) unit; lane = corner-slot (lane>>3) x channel-octet (lane&7).
// comb (B*LQ, 432) f32: cols 0..287 = offsets, 288..431 = logits.
// ---------------------------------------------------------------------------
__global__ __launch_bounds__(256) void sample_kernel(
    const bf16*  __restrict__ value,
    const float* __restrict__ comb,
    bf16*        __restrict__ attn)
{
    int wg = xcd_swz(blockIdx.x, gridDim.x);
    int unit = __builtin_amdgcn_readfirstlane((wg << 2) + (threadIdx.x >> 6));
    int lane = threadIdx.x & 63;
    int o   = lane & 7;          // channel octet -> channels o*8..o*8+7
    int c8  = lane >> 3;         // corner slot 0..7
    int k   = c8 & 3;
    int dx  = k & 1, dy = k >> 1;
    int h  = unit % NH;
    int bq = unit / NH;
    int q  = bq & (LQ - 1);
    int b  = bq >> 12;

    const float* rowp = comb + (size_t)bq * 432;
    const float* ob = rowp + h * 24;
    const float* lg = rowp + 288 + h * 12;

    float l[12];
    float mx = -1e30f;
    #pragma unroll
    for (int i = 0; i < 12; i++) { l[i] = lg[i]; mx = fmaxf(mx, l[i]); }
    float den = 0.f;
    #pragma unroll
    for (int i = 0; i < 12; i++) { l[i] = __expf(l[i] - mx); den += l[i]; }
    float rden = 1.f / den;
    #pragma unroll
    for (int i = 0; i < 12; i++) l[i] *= rden;

    float rx = ((q & 63) + 0.5f) * (1.f / 64.f);
    float ry = ((q >> 6) + 0.5f) * (1.f / 64.f);

    float acc[8] = {0.f};

    #pragma unroll
    for (int it = 0; it < 6; it++) {
        const int wl = (it < 2) ? 112 : (it < 4 ? 56 : 28);
        const int sl = (it < 2) ? 0   : (it < 4 ? 12544 : 15680);
        int s = it * 2 + ((lane >> 5) & 1);
        float ox = ob[s * 2 + 0];
        float oy = ob[s * 2 + 1];
        float x = rx * wl + ox - 0.5f;
        float y = ry * wl + oy - 0.5f;
        float xf = floorf(x), yf = floorf(y);
        float wx = x - xf,  wy = y - yf;
        int xi = (int)xf + dx;
        int yi = (int)yf + dy;
        bool valid = ((unsigned)xi < (unsigned)wl) & ((unsigned)yi < (unsigned)wl);
        int xc = min(max(xi, 0), wl - 1);
        int yc = min(max(yi, 0), wl - 1);
        int cell = b * LIN + sl + yc * wl + xc;
        const uint4* vp = (const uint4*)(value + ((size_t)cell * NH + h) * HD + o * 8);
        uint4 v = *vp;
        float aw = (lane & 32) ? l[it * 2 + 1] : l[it * 2];
        float bw = (dx ? wx : 1.f - wx) * (dy ? wy : 1.f - wy);
        float w = valid ? aw * bw : 0.f;
        const unsigned* u = (const unsigned*)&v;
        #pragma unroll
        for (int j = 0; j < 4; j++) {
            float f0 = __uint_as_float(u[j] << 16);
            float f1 = __uint_as_float(u[j] & 0xFFFF0000u);
            acc[j * 2 + 0] = fmaf(w, f0, acc[j * 2 + 0]);
            acc[j * 2 + 1] = fmaf(w, f1, acc[j * 2 + 1]);
        }
    }

    #pragma unroll
    for (int m = 8; m <= 32; m <<= 1) {
        #pragma unroll
        for (int j = 0; j < 8; j++)
            acc[j] += __shfl_xor(acc[j], m);
    }

    if (c8 == 0) {
        union { bf16 h8[8]; uint4 u4; } r;
        #pragma unroll
        for (int j = 0; j < 8; j++) r.h8[j] = __float2bfloat16(acc[j]);
        *(uint4*)(attn + (size_t)bq * DM + h * HD + o * 8) = r.u4;
    }
}

// ---------------------------------------------------------------------------
extern "C" void kernel_launch(void* const* d_in, const int* in_sizes, int n_in,
                              void* d_out, int out_size, void* d_ws, size_t ws_size,
                              hipStream_t stream)
{
    const float* query  = (const float*)d_in[0];
    const float* feat   = (const float*)d_in[1];
    const float* ln_q_g = (const float*)d_in[2];
    const float* ln_q_b = (const float*)d_in[3];
    const float* ln_f_g = (const float*)d_in[4];
    const float* ln_f_b = (const float*)d_in[5];
    const float* W_off  = (const float*)d_in[6];
    const float* b_off  = (const float*)d_in[7];
    const float* W_attn = (const float*)d_in[8];
    const float* b_attn = (const float*)d_in[9];
    const float* W_val  = (const float*)d_in[10];
    const float* b_val  = (const float*)d_in[11];
    const float* W_out  = (const float*)d_in[12];
    const float* b_out  = (const float*)d_in[13];
    const float* gamma  = (const float*)d_in[14];
    float* out = (float*)d_out;

    char* ws = (char*)d_ws;
    char* od = (char*)d_out;
    const int M_F = BB * LIN;   // 65856
    const int M_Q = BB * LQ;    // 16384

    // ws layout (227,475,456 B proven):
    bf16*  value  = (bf16*)(ws);
    bf16*  f_ln   = (bf16*)(ws + 101154816);
    bf16*  Wt_out = (bf16*)(ws + 101154816);
    bf16*  q_ln   = (bf16*)(ws + 202309632);
    bf16*  attn   = (bf16*)(ws + 202309632);

    // d_out as scratch (dead before final GEMM):
    bf16*  Wt_val  = (bf16*)(od);
    bf16*  Wt_comb = (bf16*)(od + 1179648);
    float* comb    = (float*)(od + 2162688);

    // 1. weight cast/transpose
    cast_transpose<<<dim3(24, 24), 256, 0, stream>>>(W_val, Wt_val, 768);
    cast_transpose<<<dim3(9, 24), 256, 0, stream>>>(W_off, Wt_comb, 288);
    cast_transpose<<<dim3(7, 24), 256, 0, stream>>>(
        W_attn, Wt_comb + (size_t)288 * K_DIM, 144);

    // 2. LayerNorms (wave-per-row; rows are multiples of 4)
    ln_kernel<<<M_F / 4, 256, 0, stream>>>(feat, ln_f_g, ln_f_b, f_ln);
    ln_kernel<<<M_Q / 4, 256, 0, stream>>>(query, ln_q_g, ln_q_b, q_ln);

    // 3. value = f_ln @ W_val + b_val (bf16) — 2-phase + swizzle
    mfma_gemm_2ph<<<dim3(6, (M_F + 127) / 128), 256, 0, stream>>>(
        f_ln, Wt_val, b_val, value, nullptr, nullptr, nullptr, M_F, DM, 0, 0);

    // 4. Wt_out into f_ln's (now dead) region
    cast_transpose<<<dim3(24, 24), 256, 0, stream>>>(W_out, Wt_out, 768);

    // 5. comb = q_ln @ [W_off | W_attn] + [b_off | b_attn] (f32, N=432) — pipe
    mfma_gemm_pipe<<<dim3(4, M_Q / 128), 256, 0, stream>>>(
        q_ln, Wt_comb, b_off, comb, nullptr, nullptr, b_attn, M_Q, 432, 3, 288);

    // 6. deformable sampling -> attn (bf16)
    sample_kernel<<<(M_Q * NH) / 4, 256, 0, stream>>>(value, comb, attn);

    // 7. out = query + gamma * (attn @ W_out + b_out) — pipe
    mfma_gemm_pipe<<<dim3(6, M_Q / 128), 256, 0, stream>>>(
        attn, Wt_out, b_out, out, query, gamma, nullptr, M_Q, DM, 2, 0);
}

// Round 5
// 771.498 us; speedup vs baseline: 1.0281x; 1.0281x over previous
//
#include <hip/hip_runtime.h>
#include <hip/hip_bf16.h>

typedef __hip_bfloat16 bf16;

// Problem constants
#define BB    4
#define LQ    4096
#define LIN   16464
#define DM    768
#define NH    12
#define HD    64
#define K_DIM 768
// Levels: (112,112),(56,56),(28,28); starts 0,12544,15680; query grid 64x64

typedef __attribute__((ext_vector_type(8))) __bf16 bfrag;
typedef __attribute__((ext_vector_type(4))) float  ffrag;

// ---------------------------------------------------------------------------
// async global->LDS 16B per lane (LDS dest is wave-uniform base + lane*16)
// ---------------------------------------------------------------------------
__device__ __forceinline__ void g2l16(const void* g, void* l) {
    __builtin_amdgcn_global_load_lds(
        (const __attribute__((address_space(1))) void*)g,
        (__attribute__((address_space(3))) void*)l, 16, 0, 0);
}

// bijective XCD-chunk swizzle (m204)
__device__ __forceinline__ int xcd_swz(int orig, int nwg) {
    int xcd = orig & 7, within = orig >> 3;
    int q = nwg >> 3, r = nwg & 7;
    return (xcd < r ? xcd * (q + 1) : r * (q + 1) + (xcd - r) * q) + within;
}

// ---------------------------------------------------------------------------
// LayerNorm over last dim 768: one wave per row, 4 rows/block.
// ---------------------------------------------------------------------------
__global__ __launch_bounds__(256) void ln_kernel(
    const float* __restrict__ x, const float* __restrict__ g,
    const float* __restrict__ beta, bf16* __restrict__ y)
{
    int r = blockIdx.x * 4 + (threadIdx.x >> 6);
    int lane = threadIdx.x & 63;
    const float4* xr = (const float4*)(x + (size_t)r * DM);
    float4 v[3];
    #pragma unroll
    for (int i = 0; i < 3; i++) v[i] = xr[lane + 64 * i];
    float s = 0.f, ss = 0.f;
    #pragma unroll
    for (int i = 0; i < 3; i++) {
        s  += v[i].x + v[i].y + v[i].z + v[i].w;
        ss += v[i].x * v[i].x + v[i].y * v[i].y + v[i].z * v[i].z + v[i].w * v[i].w;
    }
    #pragma unroll
    for (int m = 1; m <= 32; m <<= 1) {
        s  += __shfl_xor(s, m);
        ss += __shfl_xor(ss, m);
    }
    float mean = s * (1.f / DM);
    float inv  = rsqrtf(ss * (1.f / DM) - mean * mean + 1e-6f);
    bf16* yr = y + (size_t)r * DM;
    #pragma unroll
    for (int i = 0; i < 3; i++) {
        float4 gg = ((const float4*)g)[lane + 64 * i];
        float4 bb = ((const float4*)beta)[lane + 64 * i];
        union { bf16 h[4]; uint2 u; } p;
        p.h[0] = __float2bfloat16((v[i].x - mean) * inv * gg.x + bb.x);
        p.h[1] = __float2bfloat16((v[i].y - mean) * inv * gg.y + bb.y);
        p.h[2] = __float2bfloat16((v[i].z - mean) * inv * gg.z + bb.z);
        p.h[3] = __float2bfloat16((v[i].w - mean) * inv * gg.w + bb.w);
        *(uint2*)(yr + (lane + 64 * i) * 4) = p.u;
    }
}

// ---------------------------------------------------------------------------
// Cast + transpose weights: W (768 x N f32, row-major) -> Wt (gridX*32 x 768 bf16)
// ---------------------------------------------------------------------------
__global__ __launch_bounds__(256) void cast_transpose(
    const float* __restrict__ W, bf16* __restrict__ Wt, int N)
{
    __shared__ float t[32][33];
    int n0 = blockIdx.x * 32, k0 = blockIdx.y * 32;
    int tx = threadIdx.x & 31, ty = threadIdx.x >> 5;  // ty 0..7
    #pragma unroll
    for (int i = 0; i < 4; i++) {
        int k = k0 + ty + i * 8;
        int n = n0 + tx;
        t[ty + i * 8][tx] = (n < N) ? W[(size_t)k * N + n] : 0.f;
    }
    __syncthreads();
    #pragma unroll
    for (int i = 0; i < 4; i++) {
        int n = n0 + ty + i * 8;
        Wt[(size_t)n * K_DIM + k0 + tx] = __float2bfloat16(t[tx][ty + i * 8]);
    }
}

// ---------------------------------------------------------------------------
// Shared epilogue: C/D layout col = lane&15, row = (lane>>4)*4 + reg
// ---------------------------------------------------------------------------
__device__ __forceinline__ void gemm_epilogue(
    ffrag acc[4][4], int bm, int bn, int wr, int wc, int lane,
    const float* bias, void* C, const float* resid, const float* gamma,
    const float* bias2, int M, int N, int mode, int nsplit)
{
    int mrow = lane & 15;
    int q4 = (lane >> 4) * 4;
    #pragma unroll
    for (int i = 0; i < 4; i++) {
        #pragma unroll
        for (int rr = 0; rr < 4; rr++) {
            int rg = bm + wr + i * 16 + q4 + rr;
            if (rg < M) {
                #pragma unroll
                for (int j = 0; j < 4; j++) {
                    int cg = bn + wc + j * 16 + mrow;
                    if (cg < N) {
                        float bv = (mode == 3 && cg >= nsplit) ? bias2[cg - nsplit]
                                                               : bias[cg];
                        float v = acc[i][j][rr] + bv;
                        size_t idx = (size_t)rg * N + cg;
                        if (mode == 0)      ((bf16*)C)[idx]  = __float2bfloat16(v);
                        else if (mode == 2) ((float*)C)[idx] = resid[idx] + gamma[cg] * v;
                        else                ((float*)C)[idx] = v;
                    }
                }
            }
        }
    }
}

// ---------------------------------------------------------------------------
// MFMA bf16 GEMM, T3 minimum-2-phase recipe (guide §5.5):
// BK=32 double-buffer in 32 KB (occupancy preserved vs single-buffer).
// Per K-step: STAGE next tile FIRST -> ds_read cur + MFMA (setprio) ->
// ONE vmcnt(0)+s_barrier AFTER compute (drain overlaps the compute, not
// exposed as in __syncthreads-before-compute). WAR-safe: each wave's
// lgkmcnt-gated MFMA guarantees ds_read data in registers before barrier.
// XOR slot-swizzle (conflict-free, R3-verified) + XCD block swizzle.
// TAG only differentiates mangled names so rocprof separates the 3 GEMMs.
// ---------------------------------------------------------------------------
template<int TAG>
__global__ __launch_bounds__(256) void mfma_gemm_t(
    const bf16*  __restrict__ A,
    const bf16*  __restrict__ Bt,
    const float* __restrict__ bias,
    void*        __restrict__ C,
    const float* __restrict__ resid,
    const float* __restrict__ gamma,
    const float* __restrict__ bias2,
    int M, int N, int mode, int nsplit)
{
    __shared__ __align__(16) char lds[32768];   // 2 buffers x (A 8K + B 8K)

    int tid  = threadIdx.x;
    int lane = tid & 63;

    int nwg  = gridDim.x * gridDim.y;
    int orig = blockIdx.y * gridDim.x + blockIdx.x;
    int wg = xcd_swz(orig, nwg);
    int bn = (wg % gridDim.x) * 128;
    int bm = (wg / gridDim.x) * 128;

    int wave = tid >> 6;
    int wr = (wave & 1) * 64, wc = (wave >> 1) * 64;

    ffrag acc[4][4] = {};

    // staging: thread covers rows rA and rA+64, slot tid&3; global k-octet
    // pre-swizzled (slot s of row r holds k-octet s^((r>>1)&3)) so the LDS
    // dest stays linear for global_load_lds (rule 21).
    int rA = tid >> 2;                       // 0..63
    int kb = (((tid & 3) ^ ((rA >> 1) & 3)) * 8);
    int ra0 = min(bm + rA, M - 1), ra1 = min(bm + 64 + rA, M - 1);
    const bf16* gA0 = A  + (size_t)ra0 * K_DIM + kb;
    const bf16* gA1 = A  + (size_t)ra1 * K_DIM + kb;
    const bf16* gB0 = Bt + (size_t)(bn + rA) * K_DIM + kb;
    const bf16* gB1 = Bt + (size_t)(bn + 64 + rA) * K_DIM + kb;

    int mrow = lane & 15;
    // read-side swizzled k-octet: slot = (lane>>4) ^ ((row>>1)&3)
    int kqs  = (((lane >> 4) ^ ((mrow >> 1) & 3)) * 8);

    auto stage = [&](char* buf, int kt) {
        const int ko = kt * 32;
        g2l16(gA0 + ko, buf + tid * 16);
        g2l16(gA1 + ko, buf + tid * 16 + 4096);
        g2l16(gB0 + ko, buf + 8192 + tid * 16);
        g2l16(gB1 + ko, buf + 8192 + tid * 16 + 4096);
    };

    // prologue: fill buffer 0, drain, barrier
    stage(lds, 0);
    asm volatile("s_waitcnt vmcnt(0)" ::: "memory");
    __builtin_amdgcn_s_barrier();

    #pragma unroll
    for (int kt = 0; kt < 24; kt++) {
        char* cur = lds + (kt & 1) * 16384;
        char* nxt = lds + ((kt & 1) ^ 1) * 16384;
        if (kt + 1 < 24) stage(nxt, kt + 1);   // issue BEFORE compute

        bfrag a[4], b[4];
        #pragma unroll
        for (int t = 0; t < 4; t++) {
            a[t] = *(const bfrag*)(cur + ((wr + t * 16 + mrow) * 32 + kqs) * 2);
            b[t] = *(const bfrag*)(cur + 8192 + ((wc + t * 16 + mrow) * 32 + kqs) * 2);
        }
        __builtin_amdgcn_s_setprio(1);
        #pragma unroll
        for (int i = 0; i < 4; i++)
            #pragma unroll
            for (int j = 0; j < 4; j++)
                acc[i][j] = __builtin_amdgcn_mfma_f32_16x16x32_bf16(
                    a[i], b[j], acc[i][j], 0, 0, 0);
        __builtin_amdgcn_s_setprio(0);

        // single drain+barrier per K-step, AFTER compute: the 4 stage loads
        // had the whole ds_read+MFMA phase to land.
        asm volatile("s_waitcnt vmcnt(0)" ::: "memory");
        __builtin_amdgcn_s_barrier();
    }

    gemm_epilogue(acc, bm, bn, wr, wc, lane, bias, C, resid, gamma, bias2,
                  M, N, mode, nsplit);
}

// ---------------------------------------------------------------------------
// Deformable sampling, corner-parallel:
// one wave per (b,q,h) unit; lane = corner-slot (lane>>3) x channel-octet (lane&7).
// comb (B*LQ, 432) f32: cols 0..287 = offsets, 288..431 = logits.
// ---------------------------------------------------------------------------
__global__ __launch_bounds__(256) void sample_kernel(
    const bf16*  __restrict__ value,
    const float* __restrict__ comb,
    bf16*        __restrict__ attn)
{
    int wg = xcd_swz(blockIdx.x, gridDim.x);
    int unit = __builtin_amdgcn_readfirstlane((wg << 2) + (threadIdx.x >> 6));
    int lane = threadIdx.x & 63;
    int o   = lane & 7;          // channel octet -> channels o*8..o*8+7
    int c8  = lane >> 3;         // corner slot 0..7
    int k   = c8 & 3;
    int dx  = k & 1, dy = k >> 1;
    int h  = unit % NH;
    int bq = unit / NH;
    int q  = bq & (LQ - 1);
    int b  = bq >> 12;

    const float* rowp = comb + (size_t)bq * 432;
    const float* ob = rowp + h * 24;
    const float* lg = rowp + 288 + h * 12;

    float l[12];
    float mx = -1e30f;
    #pragma unroll
    for (int i = 0; i < 12; i++) { l[i] = lg[i]; mx = fmaxf(mx, l[i]); }
    float den = 0.f;
    #pragma unroll
    for (int i = 0; i < 12; i++) { l[i] = __expf(l[i] - mx); den += l[i]; }
    float rden = 1.f / den;
    #pragma unroll
    for (int i = 0; i < 12; i++) l[i] *= rden;

    float rx = ((q & 63) + 0.5f) * (1.f / 64.f);
    float ry = ((q >> 6) + 0.5f) * (1.f / 64.f);

    float acc[8] = {0.f};

    #pragma unroll
    for (int it = 0; it < 6; it++) {
        const int wl = (it < 2) ? 112 : (it < 4 ? 56 : 28);
        const int sl = (it < 2) ? 0   : (it < 4 ? 12544 : 15680);
        int s = it * 2 + ((lane >> 5) & 1);
        float ox = ob[s * 2 + 0];
        float oy = ob[s * 2 + 1];
        float x = rx * wl + ox - 0.5f;
        float y = ry * wl + oy - 0.5f;
        float xf = floorf(x), yf = floorf(y);
        float wx = x - xf,  wy = y - yf;
        int xi = (int)xf + dx;
        int yi = (int)yf + dy;
        bool valid = ((unsigned)xi < (unsigned)wl) & ((unsigned)yi < (unsigned)wl);
        int xc = min(max(xi, 0), wl - 1);
        int yc = min(max(yi, 0), wl - 1);
        int cell = b * LIN + sl + yc * wl + xc;
        const uint4* vp = (const uint4*)(value + ((size_t)cell * NH + h) * HD + o * 8);
        uint4 v = *vp;
        float aw = (lane & 32) ? l[it * 2 + 1] : l[it * 2];
        float bw = (dx ? wx : 1.f - wx) * (dy ? wy : 1.f - wy);
        float w = valid ? aw * bw : 0.f;
        const unsigned* u = (const unsigned*)&v;
        #pragma unroll
        for (int j = 0; j < 4; j++) {
            float f0 = __uint_as_float(u[j] << 16);
            float f1 = __uint_as_float(u[j] & 0xFFFF0000u);
            acc[j * 2 + 0] = fmaf(w, f0, acc[j * 2 + 0]);
            acc[j * 2 + 1] = fmaf(w, f1, acc[j * 2 + 1]);
        }
    }

    #pragma unroll
    for (int m = 8; m <= 32; m <<= 1) {
        #pragma unroll
        for (int j = 0; j < 8; j++)
            acc[j] += __shfl_xor(acc[j], m);
    }

    if (c8 == 0) {
        union { bf16 h8[8]; uint4 u4; } r;
        #pragma unroll
        for (int j = 0; j < 8; j++) r.h8[j] = __float2bfloat16(acc[j]);
        *(uint4*)(attn + (size_t)bq * DM + h * HD + o * 8) = r.u4;
    }
}

// ---------------------------------------------------------------------------
extern "C" void kernel_launch(void* const* d_in, const int* in_sizes, int n_in,
                              void* d_out, int out_size, void* d_ws, size_t ws_size,
                              hipStream_t stream)
{
    const float* query  = (const float*)d_in[0];
    const float* feat   = (const float*)d_in[1];
    const float* ln_q_g = (const float*)d_in[2];
    const float* ln_q_b = (const float*)d_in[3];
    const float* ln_f_g = (const float*)d_in[4];
    const float* ln_f_b = (const float*)d_in[5];
    const float* W_off  = (const float*)d_in[6];
    const float* b_off  = (const float*)d_in[7];
    const float* W_attn = (const float*)d_in[8];
    const float* b_attn = (const float*)d_in[9];
    const float* W_val  = (const float*)d_in[10];
    const float* b_val  = (const float*)d_in[11];
    const float* W_out  = (const float*)d_in[12];
    const float* b_out  = (const float*)d_in[13];
    const float* gamma  = (const float*)d_in[14];
    float* out = (float*)d_out;

    char* ws = (char*)d_ws;
    char* od = (char*)d_out;
    const int M_F = BB * LIN;   // 65856
    const int M_Q = BB * LQ;    // 16384

    // ws layout (227,475,456 B proven):
    bf16*  value  = (bf16*)(ws);
    bf16*  f_ln   = (bf16*)(ws + 101154816);
    bf16*  Wt_out = (bf16*)(ws + 101154816);
    bf16*  q_ln   = (bf16*)(ws + 202309632);
    bf16*  attn   = (bf16*)(ws + 202309632);

    // d_out as scratch (dead before final GEMM):
    bf16*  Wt_val  = (bf16*)(od);
    bf16*  Wt_comb = (bf16*)(od + 1179648);
    float* comb    = (float*)(od + 2162688);

    // 1. weight cast/transpose
    cast_transpose<<<dim3(24, 24), 256, 0, stream>>>(W_val, Wt_val, 768);
    cast_transpose<<<dim3(9, 24), 256, 0, stream>>>(W_off, Wt_comb, 288);
    cast_transpose<<<dim3(7, 24), 256, 0, stream>>>(
        W_attn, Wt_comb + (size_t)288 * K_DIM, 144);

    // 2. LayerNorms (wave-per-row; rows are multiples of 4)
    ln_kernel<<<M_F / 4, 256, 0, stream>>>(feat, ln_f_g, ln_f_b, f_ln);
    ln_kernel<<<M_Q / 4, 256, 0, stream>>>(query, ln_q_g, ln_q_b, q_ln);

    // 3. value = f_ln @ W_val + b_val (bf16)
    mfma_gemm_t<0><<<dim3(6, (M_F + 127) / 128), 256, 0, stream>>>(
        f_ln, Wt_val, b_val, value, nullptr, nullptr, nullptr, M_F, DM, 0, 0);

    // 4. Wt_out into f_ln's (now dead) region
    cast_transpose<<<dim3(24, 24), 256, 0, stream>>>(W_out, Wt_out, 768);

    // 5. comb = q_ln @ [W_off | W_attn] + [b_off | b_attn] (f32, N=432)
    mfma_gemm_t<1><<<dim3(4, M_Q / 128), 256, 0, stream>>>(
        q_ln, Wt_comb, b_off, comb, nullptr, nullptr, b_attn, M_Q, 432, 3, 288);

    // 6. deformable sampling -> attn (bf16)
    sample_kernel<<<(M_Q * NH) / 4, 256, 0, stream>>>(value, comb, attn);

    // 7. out = query + gamma * (attn @ W_out + b_out)
    mfma_gemm_t<2><<<dim3(6, M_Q / 128), 256, 0, stream>>>(
        attn, Wt_out, b_out, out, query, gamma, nullptr, M_Q, DM, 2, 0);
}

// Round 6
// 702.573 us; speedup vs baseline: 1.1290x; 1.0981x over previous
//
#include <hip/hip_runtime.h>
#include <hip/hip_bf16.h>

typedef __hip_bfloat16 bf16;

// Problem constants
#define BB    4
#define LQ    4096
#define LIN   16464
#define DM    768
#define NH    12
#define HD    64
#define K_DIM 768
// Levels: (112,112),(56,56),(28,28); starts 0,12544,15680; query grid 64x64

typedef __attribute__((ext_vector_type(8))) __bf16 bfrag;
typedef __attribute__((ext_vector_type(4))) float  ffrag;

// ---------------------------------------------------------------------------
// async global->LDS 16B per lane (LDS dest is wave-uniform base + lane*16)
// ---------------------------------------------------------------------------
__device__ __forceinline__ void g2l16(const void* g, void* l) {
    __builtin_amdgcn_global_load_lds(
        (const __attribute__((address_space(1))) void*)g,
        (__attribute__((address_space(3))) void*)l, 16, 0, 0);
}

// bijective XCD-chunk swizzle (m204)
__device__ __forceinline__ int xcd_swz(int orig, int nwg) {
    int xcd = orig & 7, within = orig >> 3;
    int q = nwg >> 3, r = nwg & 7;
    return (xcd < r ? xcd * (q + 1) : r * (q + 1) + (xcd - r) * q) + within;
}

// ---------------------------------------------------------------------------
// LayerNorm over last dim 768: one wave per row, 4 rows/block.
// ---------------------------------------------------------------------------
__global__ __launch_bounds__(256) void ln_kernel(
    const float* __restrict__ x, const float* __restrict__ g,
    const float* __restrict__ beta, bf16* __restrict__ y)
{
    int r = blockIdx.x * 4 + (threadIdx.x >> 6);
    int lane = threadIdx.x & 63;
    const float4* xr = (const float4*)(x + (size_t)r * DM);
    float4 v[3];
    #pragma unroll
    for (int i = 0; i < 3; i++) v[i] = xr[lane + 64 * i];
    float s = 0.f, ss = 0.f;
    #pragma unroll
    for (int i = 0; i < 3; i++) {
        s  += v[i].x + v[i].y + v[i].z + v[i].w;
        ss += v[i].x * v[i].x + v[i].y * v[i].y + v[i].z * v[i].z + v[i].w * v[i].w;
    }
    #pragma unroll
    for (int m = 1; m <= 32; m <<= 1) {
        s  += __shfl_xor(s, m);
        ss += __shfl_xor(ss, m);
    }
    float mean = s * (1.f / DM);
    float inv  = rsqrtf(ss * (1.f / DM) - mean * mean + 1e-6f);
    bf16* yr = y + (size_t)r * DM;
    #pragma unroll
    for (int i = 0; i < 3; i++) {
        float4 gg = ((const float4*)g)[lane + 64 * i];
        float4 bb = ((const float4*)beta)[lane + 64 * i];
        union { bf16 h[4]; uint2 u; } p;
        p.h[0] = __float2bfloat16((v[i].x - mean) * inv * gg.x + bb.x);
        p.h[1] = __float2bfloat16((v[i].y - mean) * inv * gg.y + bb.y);
        p.h[2] = __float2bfloat16((v[i].z - mean) * inv * gg.z + bb.z);
        p.h[3] = __float2bfloat16((v[i].w - mean) * inv * gg.w + bb.w);
        *(uint2*)(yr + (lane + 64 * i) * 4) = p.u;
    }
}

// ---------------------------------------------------------------------------
// Cast + transpose weights: W (768 x N f32, row-major) -> Wt (gridX*32 x 768 bf16)
// ---------------------------------------------------------------------------
__global__ __launch_bounds__(256) void cast_transpose(
    const float* __restrict__ W, bf16* __restrict__ Wt, int N)
{
    __shared__ float t[32][33];
    int n0 = blockIdx.x * 32, k0 = blockIdx.y * 32;
    int tx = threadIdx.x & 31, ty = threadIdx.x >> 5;  // ty 0..7
    #pragma unroll
    for (int i = 0; i < 4; i++) {
        int k = k0 + ty + i * 8;
        int n = n0 + tx;
        t[ty + i * 8][tx] = (n < N) ? W[(size_t)k * N + n] : 0.f;
    }
    __syncthreads();
    #pragma unroll
    for (int i = 0; i < 4; i++) {
        int n = n0 + ty + i * 8;
        Wt[(size_t)n * K_DIM + k0 + tx] = __float2bfloat16(t[tx][ty + i * 8]);
    }
}

// ---------------------------------------------------------------------------
// 256x256-tile 8-wave GEMM (m201 8-phase template geometry), bf16 out:
// C(M,768) = A(M,768) @ Wt(768,768)^T + bias.
// BK=64, 12 K-tiles; LDS 128KB = 2 dbuf x (A 32K + B 32K), halves of 128 rows.
// 512 threads = 8 waves (2M x 4N); per-wave output 128x64 = 8x4 16x16 frags.
// Per K-tile: 4 phases x 16 MFMA; b-frags (8) read once in phase 0, held in
// regs; per phase stage 1 half-tile (2 global_load_lds) of K-tile kt+1.
// Counted vmcnt(2) at K-tile entry (kt+1's first half-tile stays in flight);
// vmcnt(0) only at the last K-tile. setprio(1) around MFMA clusters.
// XOR slot-swizzle slot^=(row&7) (pre-swizzled global source, rule 21).
// WAR-safe: compiler lgkmcnt gates MFMA before each wave reaches a barrier,
// so buf being restaged is never under outstanding reads past a barrier.
// ---------------------------------------------------------------------------
__global__ __launch_bounds__(512) void gemm256_value(
    const bf16*  __restrict__ A,
    const bf16*  __restrict__ Bt,
    const float* __restrict__ bias,
    bf16*        __restrict__ C,
    int M, int N)
{
    __shared__ __align__(16) char lds[131072];

    int tid  = threadIdx.x;
    int lane = tid & 63;
    int wave = tid >> 6;

    int nwg  = gridDim.x * gridDim.y;
    int orig = blockIdx.y * gridDim.x + blockIdx.x;
    int wg   = xcd_swz(orig, nwg);
    int bn = (wg % gridDim.x) * 256;
    int bm = (wg / gridDim.x) * 256;

    // wave -> output sub-tile: rows [ahalf*128, +128), cols [(wave&3)*64, +64)
    int ahalf = wave >> 2;            // 0/1
    int wc    = (wave & 3) * 64;
    int bhalf = (wave & 3) >> 1;      // which B half (cols 0-127 / 128-255)
    int bcb   = (wave & 1) * 64;      // col base within B half

    int ln15 = lane & 15, g = lane >> 4, l7 = lane & 7;

    ffrag acc[8][4] = {};

    // ---- staging geometry: per half-tile (128 rows x 64 k) 2 loads of
    // 512 thr x 16B. thread covers row r_loc (+0/+64), slot tid&7.
    // LDS slot s of row r holds global k-octet s^(r&7) (involution).
    int r_loc = tid >> 3;                         // 0..63
    int koff  = (((tid & 7) ^ (r_loc & 7)) * 8);  // pre-swizzled k-octet

    const bf16* gA[2][2];
    const bf16* gB[2][2];
    #pragma unroll
    for (int h = 0; h < 2; h++)
        #pragma unroll
        for (int ld = 0; ld < 2; ld++) {
            int ra = min(bm + h * 128 + ld * 64 + r_loc, M - 1);
            gA[h][ld] = A  + (size_t)ra * K_DIM + koff;
            int cb = bn + h * 128 + ld * 64 + r_loc;     // N=768 exact
            gB[h][ld] = Bt + (size_t)cb * K_DIM + koff;
        }

    auto stageA = [&](char* buf, int h, int kt) {
        g2l16(gA[h][0] + kt * 64, buf + h * 16384 + tid * 16);
        g2l16(gA[h][1] + kt * 64, buf + h * 16384 + 8192 + tid * 16);
    };
    auto stageB = [&](char* buf, int h, int kt) {
        g2l16(gB[h][0] + kt * 64, buf + 32768 + h * 16384 + tid * 16);
        g2l16(gB[h][1] + kt * 64, buf + 32768 + h * 16384 + 8192 + tid * 16);
    };

    // prologue: stage K-tile 0 into buf0 (8 loads/wave)
    stageA(lds, 0, 0); stageA(lds, 1, 0); stageB(lds, 0, 0); stageB(lds, 1, 0);

    // read-side swizzled slot byte offset: slot = (ks*4 + g) ^ l7
    int sby[2];
    sby[0] = ((0 * 4 + g) ^ l7) * 16;
    sby[1] = ((1 * 4 + g) ^ l7) * 16;

    #pragma unroll
    for (int kt = 0; kt < 12; kt++) {
        char* cur = lds + (kt & 1) * 65536;
        char* nxt = lds + ((kt & 1) ^ 1) * 65536;
        const char* Ac = cur + ahalf * 16384;
        const char* Bc = cur + 32768 + bhalf * 16384;

        // ---- phase 0: stage A-h0 of kt+1, counted wait, barrier ----
        if (kt + 1 < 12) {
            stageA(nxt, 0, kt + 1);
            asm volatile("s_waitcnt vmcnt(2)" ::: "memory");
        } else {
            asm volatile("s_waitcnt vmcnt(0)" ::: "memory");
        }
        __builtin_amdgcn_s_barrier();

        bfrag bf[4][2];
        #pragma unroll
        for (int nc = 0; nc < 4; nc++)
            #pragma unroll
            for (int ks = 0; ks < 2; ks++)
                bf[nc][ks] = *(const bfrag*)(Bc + (bcb + nc * 16 + ln15) * 128 + sby[ks]);
        {
            bfrag af[2][2];
            #pragma unroll
            for (int m2 = 0; m2 < 2; m2++)
                #pragma unroll
                for (int ks = 0; ks < 2; ks++)
                    af[m2][ks] = *(const bfrag*)(Ac + (m2 * 16 + ln15) * 128 + sby[ks]);
            __builtin_amdgcn_s_setprio(1);
            #pragma unroll
            for (int m2 = 0; m2 < 2; m2++)
                #pragma unroll
                for (int nc = 0; nc < 4; nc++)
                    #pragma unroll
                    for (int ks = 0; ks < 2; ks++)
                        acc[m2][nc] = __builtin_amdgcn_mfma_f32_16x16x32_bf16(
                            af[m2][ks], bf[nc][ks], acc[m2][nc], 0, 0, 0);
            __builtin_amdgcn_s_setprio(0);
        }
        __builtin_amdgcn_s_barrier();

        // ---- phases 1..3: stage one half-tile, 2 frag-rows x 4 cols ----
        #pragma unroll
        for (int qd = 1; qd < 4; qd++) {
            if (kt + 1 < 12) {
                if (qd == 1) stageA(nxt, 1, kt + 1);
                else if (qd == 2) stageB(nxt, 0, kt + 1);
                else stageB(nxt, 1, kt + 1);
            }
            bfrag af[2][2];
            #pragma unroll
            for (int m2 = 0; m2 < 2; m2++)
                #pragma unroll
                for (int ks = 0; ks < 2; ks++)
                    af[m2][ks] = *(const bfrag*)(Ac + ((qd * 2 + m2) * 16 + ln15) * 128 + sby[ks]);
            __builtin_amdgcn_s_setprio(1);
            #pragma unroll
            for (int m2 = 0; m2 < 2; m2++)
                #pragma unroll
                for (int nc = 0; nc < 4; nc++)
                    #pragma unroll
                    for (int ks = 0; ks < 2; ks++)
                        acc[qd * 2 + m2][nc] = __builtin_amdgcn_mfma_f32_16x16x32_bf16(
                            af[m2][ks], bf[nc][ks], acc[qd * 2 + m2][nc], 0, 0, 0);
            __builtin_amdgcn_s_setprio(0);
            __builtin_amdgcn_s_barrier();
        }
    }

    // epilogue: C/D layout col = lane&15, row = (lane>>4)*4 + reg
    int q4 = g * 4;
    #pragma unroll
    for (int mr = 0; mr < 8; mr++) {
        #pragma unroll
        for (int rr = 0; rr < 4; rr++) {
            int rg = bm + ahalf * 128 + mr * 16 + q4 + rr;
            if (rg < M) {
                #pragma unroll
                for (int nc = 0; nc < 4; nc++) {
                    int cg = bn + wc + nc * 16 + ln15;
                    C[(size_t)rg * N + cg] =
                        __float2bfloat16(acc[mr][nc][rr] + bias[cg]);
                }
            }
        }
    }
}

// ---------------------------------------------------------------------------
// 128x128 2-phase GEMM body (R5-verified: BK=32 dbuf in 32KB, stage-early,
// one vmcnt(0)+barrier per K-step after compute, XOR slot-swizzle, setprio).
// mode 2: f32 = resid + gamma*(acc+bias); mode 3: f32, dual bias at nsplit.
// ---------------------------------------------------------------------------
__device__ __forceinline__ void gemm128_body(
    const bf16*  __restrict__ A,
    const bf16*  __restrict__ Bt,
    const float* __restrict__ bias,
    void*        __restrict__ C,
    const float* __restrict__ resid,
    const float* __restrict__ gamma,
    const float* __restrict__ bias2,
    int M, int N, int mode, int nsplit, char* lds)
{
    int tid  = threadIdx.x;
    int lane = tid & 63;

    int nwg  = gridDim.x * gridDim.y;
    int orig = blockIdx.y * gridDim.x + blockIdx.x;
    int wg = xcd_swz(orig, nwg);
    int bn = (wg % gridDim.x) * 128;
    int bm = (wg / gridDim.x) * 128;

    int wave = tid >> 6;
    int wr = (wave & 1) * 64, wc = (wave >> 1) * 64;

    ffrag acc[4][4] = {};

    int rA = tid >> 2;                       // 0..63
    int kb = (((tid & 3) ^ ((rA >> 1) & 3)) * 8);
    int ra0 = min(bm + rA, M - 1), ra1 = min(bm + 64 + rA, M - 1);
    const bf16* gA0 = A  + (size_t)ra0 * K_DIM + kb;
    const bf16* gA1 = A  + (size_t)ra1 * K_DIM + kb;
    const bf16* gB0 = Bt + (size_t)(bn + rA) * K_DIM + kb;
    const bf16* gB1 = Bt + (size_t)(bn + 64 + rA) * K_DIM + kb;

    int mrow = lane & 15;
    int kqs  = (((lane >> 4) ^ ((mrow >> 1) & 3)) * 8);

    auto stage = [&](char* buf, int kt) {
        const int ko = kt * 32;
        g2l16(gA0 + ko, buf + tid * 16);
        g2l16(gA1 + ko, buf + tid * 16 + 4096);
        g2l16(gB0 + ko, buf + 8192 + tid * 16);
        g2l16(gB1 + ko, buf + 8192 + tid * 16 + 4096);
    };

    stage(lds, 0);
    asm volatile("s_waitcnt vmcnt(0)" ::: "memory");
    __builtin_amdgcn_s_barrier();

    #pragma unroll
    for (int kt = 0; kt < 24; kt++) {
        char* cur = lds + (kt & 1) * 16384;
        char* nxt = lds + ((kt & 1) ^ 1) * 16384;
        if (kt + 1 < 24) stage(nxt, kt + 1);

        bfrag a[4], b[4];
        #pragma unroll
        for (int t = 0; t < 4; t++) {
            a[t] = *(const bfrag*)(cur + ((wr + t * 16 + mrow) * 32 + kqs) * 2);
            b[t] = *(const bfrag*)(cur + 8192 + ((wc + t * 16 + mrow) * 32 + kqs) * 2);
        }
        __builtin_amdgcn_s_setprio(1);
        #pragma unroll
        for (int i = 0; i < 4; i++)
            #pragma unroll
            for (int j = 0; j < 4; j++)
                acc[i][j] = __builtin_amdgcn_mfma_f32_16x16x32_bf16(
                    a[i], b[j], acc[i][j], 0, 0, 0);
        __builtin_amdgcn_s_setprio(0);

        asm volatile("s_waitcnt vmcnt(0)" ::: "memory");
        __builtin_amdgcn_s_barrier();
    }

    int q4 = (lane >> 4) * 4;
    #pragma unroll
    for (int i = 0; i < 4; i++) {
        #pragma unroll
        for (int rr = 0; rr < 4; rr++) {
            int rg = bm + wr + i * 16 + q4 + rr;
            if (rg < M) {
                #pragma unroll
                for (int j = 0; j < 4; j++) {
                    int cg = bn + wc + j * 16 + mrow;
                    if (cg < N) {
                        float bv = (mode == 3 && cg >= nsplit) ? bias2[cg - nsplit]
                                                               : bias[cg];
                        float v = acc[i][j][rr] + bv;
                        size_t idx = (size_t)rg * N + cg;
                        if (mode == 2)      ((float*)C)[idx] = resid[idx] + gamma[cg] * v;
                        else                ((float*)C)[idx] = v;
                    }
                }
            }
        }
    }
}

__global__ __launch_bounds__(256) void gemm128_comb(
    const bf16* __restrict__ A, const bf16* __restrict__ Bt,
    const float* __restrict__ bias, void* __restrict__ C,
    const float* __restrict__ bias2, int M, int N, int nsplit)
{
    __shared__ __align__(16) char lds[32768];
    gemm128_body(A, Bt, bias, C, nullptr, nullptr, bias2, M, N, 3, nsplit, lds);
}

__global__ __launch_bounds__(256) void gemm128_out(
    const bf16* __restrict__ A, const bf16* __restrict__ Bt,
    const float* __restrict__ bias, void* __restrict__ C,
    const float* __restrict__ resid, const float* __restrict__ gamma,
    int M, int N)
{
    __shared__ __align__(16) char lds[32768];
    gemm128_body(A, Bt, bias, C, resid, gamma, nullptr, M, N, 2, 0, lds);
}

// ---------------------------------------------------------------------------
// Deformable sampling, corner-parallel.
// ---------------------------------------------------------------------------
__global__ __launch_bounds__(256) void sample_kernel(
    const bf16*  __restrict__ value,
    const float* __restrict__ comb,
    bf16*        __restrict__ attn)
{
    int wg = xcd_swz(blockIdx.x, gridDim.x);
    int unit = __builtin_amdgcn_readfirstlane((wg << 2) + (threadIdx.x >> 6));
    int lane = threadIdx.x & 63;
    int o   = lane & 7;          // channel octet -> channels o*8..o*8+7
    int c8  = lane >> 3;         // corner slot 0..7
    int k   = c8 & 3;
    int dx  = k & 1, dy = k >> 1;
    int h  = unit % NH;
    int bq = unit / NH;
    int q  = bq & (LQ - 1);
    int b  = bq >> 12;

    const float* rowp = comb + (size_t)bq * 432;
    const float* ob = rowp + h * 24;
    const float* lg = rowp + 288 + h * 12;

    float l[12];
    float mx = -1e30f;
    #pragma unroll
    for (int i = 0; i < 12; i++) { l[i] = lg[i]; mx = fmaxf(mx, l[i]); }
    float den = 0.f;
    #pragma unroll
    for (int i = 0; i < 12; i++) { l[i] = __expf(l[i] - mx); den += l[i]; }
    float rden = 1.f / den;
    #pragma unroll
    for (int i = 0; i < 12; i++) l[i] *= rden;

    float rx = ((q & 63) + 0.5f) * (1.f / 64.f);
    float ry = ((q >> 6) + 0.5f) * (1.f / 64.f);

    float acc[8] = {0.f};

    #pragma unroll
    for (int it = 0; it < 6; it++) {
        const int wl = (it < 2) ? 112 : (it < 4 ? 56 : 28);
        const int sl = (it < 2) ? 0   : (it < 4 ? 12544 : 15680);
        int s = it * 2 + ((lane >> 5) & 1);
        float ox = ob[s * 2 + 0];
        float oy = ob[s * 2 + 1];
        float x = rx * wl + ox - 0.5f;
        float y = ry * wl + oy - 0.5f;
        float xf = floorf(x), yf = floorf(y);
        float wx = x - xf,  wy = y - yf;
        int xi = (int)xf + dx;
        int yi = (int)yf + dy;
        bool valid = ((unsigned)xi < (unsigned)wl) & ((unsigned)yi < (unsigned)wl);
        int xc = min(max(xi, 0), wl - 1);
        int yc = min(max(yi, 0), wl - 1);
        int cell = b * LIN + sl + yc * wl + xc;
        const uint4* vp = (const uint4*)(value + ((size_t)cell * NH + h) * HD + o * 8);
        uint4 v = *vp;
        float aw = (lane & 32) ? l[it * 2 + 1] : l[it * 2];
        float bw = (dx ? wx : 1.f - wx) * (dy ? wy : 1.f - wy);
        float w = valid ? aw * bw : 0.f;
        const unsigned* u = (const unsigned*)&v;
        #pragma unroll
        for (int j = 0; j < 4; j++) {
            float f0 = __uint_as_float(u[j] << 16);
            float f1 = __uint_as_float(u[j] & 0xFFFF0000u);
            acc[j * 2 + 0] = fmaf(w, f0, acc[j * 2 + 0]);
            acc[j * 2 + 1] = fmaf(w, f1, acc[j * 2 + 1]);
        }
    }

    #pragma unroll
    for (int m = 8; m <= 32; m <<= 1) {
        #pragma unroll
        for (int j = 0; j < 8; j++)
            acc[j] += __shfl_xor(acc[j], m);
    }

    if (c8 == 0) {
        union { bf16 h8[8]; uint4 u4; } r;
        #pragma unroll
        for (int j = 0; j < 8; j++) r.h8[j] = __float2bfloat16(acc[j]);
        *(uint4*)(attn + (size_t)bq * DM + h * HD + o * 8) = r.u4;
    }
}

// ---------------------------------------------------------------------------
extern "C" void kernel_launch(void* const* d_in, const int* in_sizes, int n_in,
                              void* d_out, int out_size, void* d_ws, size_t ws_size,
                              hipStream_t stream)
{
    const float* query  = (const float*)d_in[0];
    const float* feat   = (const float*)d_in[1];
    const float* ln_q_g = (const float*)d_in[2];
    const float* ln_q_b = (const float*)d_in[3];
    const float* ln_f_g = (const float*)d_in[4];
    const float* ln_f_b = (const float*)d_in[5];
    const float* W_off  = (const float*)d_in[6];
    const float* b_off  = (const float*)d_in[7];
    const float* W_attn = (const float*)d_in[8];
    const float* b_attn = (const float*)d_in[9];
    const float* W_val  = (const float*)d_in[10];
    const float* b_val  = (const float*)d_in[11];
    const float* W_out  = (const float*)d_in[12];
    const float* b_out  = (const float*)d_in[13];
    const float* gamma  = (const float*)d_in[14];
    float* out = (float*)d_out;

    char* ws = (char*)d_ws;
    char* od = (char*)d_out;
    const int M_F = BB * LIN;   // 65856
    const int M_Q = BB * LQ;    // 16384

    // ws layout (227,475,456 B proven):
    bf16*  value  = (bf16*)(ws);
    bf16*  f_ln   = (bf16*)(ws + 101154816);
    bf16*  Wt_out = (bf16*)(ws + 101154816);
    bf16*  q_ln   = (bf16*)(ws + 202309632);
    bf16*  attn   = (bf16*)(ws + 202309632);

    // d_out as scratch (dead before final GEMM):
    bf16*  Wt_val  = (bf16*)(od);
    bf16*  Wt_comb = (bf16*)(od + 1179648);
    float* comb    = (float*)(od + 2162688);

    // 1. weight cast/transpose
    cast_transpose<<<dim3(24, 24), 256, 0, stream>>>(W_val, Wt_val, 768);
    cast_transpose<<<dim3(9, 24), 256, 0, stream>>>(W_off, Wt_comb, 288);
    cast_transpose<<<dim3(7, 24), 256, 0, stream>>>(
        W_attn, Wt_comb + (size_t)288 * K_DIM, 144);

    // 2. LayerNorms (wave-per-row; rows are multiples of 4)
    ln_kernel<<<M_F / 4, 256, 0, stream>>>(feat, ln_f_g, ln_f_b, f_ln);
    ln_kernel<<<M_Q / 4, 256, 0, stream>>>(query, ln_q_g, ln_q_b, q_ln);

    // 3. value = f_ln @ W_val + b_val (bf16) — 256²/8-wave template
    gemm256_value<<<dim3(3, (M_F + 255) / 256), 512, 0, stream>>>(
        f_ln, Wt_val, b_val, value, M_F, DM);

    // 4. Wt_out into f_ln's (now dead) region
    cast_transpose<<<dim3(24, 24), 256, 0, stream>>>(W_out, Wt_out, 768);

    // 5. comb = q_ln @ [W_off | W_attn] + [b_off | b_attn] (f32, N=432)
    gemm128_comb<<<dim3(4, M_Q / 128), 256, 0, stream>>>(
        q_ln, Wt_comb, b_off, comb, b_attn, M_Q, 432, 288);

    // 6. deformable sampling -> attn (bf16)
    sample_kernel<<<(M_Q * NH) / 4, 256, 0, stream>>>(value, comb, attn);

    // 7. out = query + gamma * (attn @ W_out + b_out)
    gemm128_out<<<dim3(6, M_Q / 128), 256, 0, stream>>>(
        attn, Wt_out, b_out, out, query, gamma, M_Q, DM);
}